// Round 4
// baseline (213.694 us; speedup 1.0000x reference)
//
#include <hip/hip_runtime.h>

typedef __attribute__((ext_vector_type(4))) float floatx4;
typedef __attribute__((ext_vector_type(8))) short shortx8;

// db4 analysis filters, TRUE-convolution orientation:
// y[m] = sum_i F[i] * xp[2m + 7 - i]  (xp reflect-padded, pl = 6 at every level)
__device__ __constant__ float DLO[8] = {
    -0.010597401784997278f, 0.032883011666982945f,
     0.030841381835986965f, -0.18703481171888114f,
    -0.02798376941698385f,  0.6308807679295904f,
     0.7148465705525415f,   0.23037781330885523f};
__device__ __constant__ float DHI[8] = {
    -0.23037781330885523f,  0.7148465705525415f,
    -0.6308807679295904f,  -0.02798376941698385f,
     0.18703481171888114f,  0.030841381835986965f,
     0.032883011666982945f, -0.010597401784997278f};

__device__ __forceinline__ unsigned short f2bf_rne(float f) {
  unsigned u = __builtin_bit_cast(unsigned, f);
  unsigned r = (u + 0x7FFFu + ((u >> 16) & 1u)) >> 16;
  return (unsigned short)r;
}

// One analysis filter-bank level. pl (left reflect pad) == 6 for n in {64,35,21}.
template <int N, int OUT>
__device__ __forceinline__ void afb(const float* x, float* lo, float* hi) {
#pragma unroll
  for (int m = 0; m < OUT; ++m) {
    float aL = 0.f, aH = 0.f;
#pragma unroll
    for (int i = 0; i < 8; ++i) {
      int s = 2 * m + 1 - i;              // 2m + 7 - i - 6
      s = (s < 0) ? -s : s;               // reflect (no edge repeat)
      s = (s >= N) ? (2 * N - 2 - s) : s;
      float v = x[s];
      aL = fmaf(DLO[i], v, aL);
      aH = fmaf(DHI[i], v, aH);
    }
    lo[m] = aL; hi[m] = aH;
  }
}

// Fused M-build + W2-build (unchanged — passed rounds 2/3).
// grid (64, 4), 256 threads. blockIdx.x = k, blockIdx.y = 16-wide tp slice.
// W2[k][tp*64+hw] = sum_t M[t][tp] * conv_w[k][t][hw], rounded to bf16.
__global__ __launch_bounds__(256) void build_w2_fused(
    const float* __restrict__ cw, unsigned short* __restrict__ W2) {
  __shared__ float Ml[84 * 64];
  __shared__ float Cl[84 * 64];
  const int k = blockIdx.x;
  const int tid = threadIdx.x;

  if (tid < 64) {  // column tid of M = DWT(e_tid)
    const int i = tid;
    float sig[64];
#pragma unroll
    for (int t = 0; t < 64; ++t) sig[t] = (t == i) ? 1.f : 0.f;
    float lo1[35], hi1[35], lo2[21], hi2[21], lo3[14], hi3[14];
    afb<64, 35>(sig, lo1, hi1);
    afb<35, 21>(lo1, lo2, hi2);
    afb<21, 14>(lo2, lo3, hi3);
#pragma unroll
    for (int t = 0; t < 14; ++t) Ml[t * 64 + i] = lo3[t];
#pragma unroll
    for (int t = 0; t < 35; ++t) Ml[(14 + t) * 64 + i] = hi1[t];
#pragma unroll
    for (int t = 0; t < 21; ++t) Ml[(49 + t) * 64 + i] = hi2[t];
#pragma unroll
    for (int t = 0; t < 14; ++t) Ml[(70 + t) * 64 + i] = hi3[t];
  }
  const float* cwk = cw + (size_t)k * (84 * 64);
  for (int idx = tid; idx < 84 * 64; idx += 256) Cl[idx] = cwk[idx];
  __syncthreads();

  const int tp  = blockIdx.y * 16 + (tid >> 4);
  const int hw0 = (tid & 15) * 4;
  float a0 = 0.f, a1 = 0.f, a2 = 0.f, a3 = 0.f;
#pragma unroll 4
  for (int t = 0; t < 84; ++t) {
    const float mv = Ml[t * 64 + tp];
    const float4 cv = *(const float4*)&Cl[t * 64 + hw0];
    a0 = fmaf(mv, cv.x, a0);
    a1 = fmaf(mv, cv.y, a1);
    a2 = fmaf(mv, cv.z, a2);
    a3 = fmaf(mv, cv.w, a3);
  }
  uint2 pk;
  pk.x = (unsigned)f2bf_rne(a0) | ((unsigned)f2bf_rne(a1) << 16);
  pk.y = (unsigned)f2bf_rne(a2) | ((unsigned)f2bf_rne(a3) << 16);
  *(uint2*)(W2 + (size_t)k * 4096 + tp * 64 + hw0) = pk;
}

// ---- GEMM main: B-in-LDS-once, barrier-free K loop, split-K=4 ----
// part[kb][8192][64] += nothing (pure store): partial sums of
// A[8192][4096(k-range kb)] x W2^T. grid (64 m-blocks, 4 kb), 512 threads.
// Each of 8 waves owns one 16-row m-tile, all 4 n-tiles, 32 K32 chunks.
// No per-chunk barriers (B is LDS-resident after one staging barrier),
// no per-chunk global B loads (round-3's L2 B-stream shared the vmcnt
// queue with the HBM A-stream and throttled the pipeline).
#define LDB 1032  // 1024 + 8 pad: row stride 2064 B = 516 dw = 4 mod 32 ->
                  // balanced 8-round b128 reads (the wave64 b128 floor)

__global__ __launch_bounds__(512) void gemm_kernel(
    const float* __restrict__ A, const unsigned short* __restrict__ W2,
    float* __restrict__ part) {
  __shared__ alignas(16) unsigned short Bs[64 * LDB];  // 129 KB

  const int tid  = threadIdx.x;
  const int lane = tid & 63;
  const int wave = tid >> 6;            // m-tile 0..7
  const int frow = lane & 15;
  const int fk   = (lane >> 4) * 8;     // 0,8,16,24
  const int kb   = blockIdx.y;
  const int m0   = blockIdx.x * 128 + wave * 16;
  const int kbase = kb * 1024;

  const float* aptr = A + (size_t)(m0 + frow) * 4096 + kbase + fk;

  // depth-4 A-ring prologue (chunks 0..3), named slots (static indexing)
  float4 al0 = *(const float4*)(aptr + 0),   ah0 = *(const float4*)(aptr + 4);
  float4 al1 = *(const float4*)(aptr + 32),  ah1 = *(const float4*)(aptr + 36);
  float4 al2 = *(const float4*)(aptr + 64),  ah2 = *(const float4*)(aptr + 68);
  float4 al3 = *(const float4*)(aptr + 96),  ah3 = *(const float4*)(aptr + 100);

  // stage W2[:, kbase..kbase+1024) into LDS once: 64 rows x 1024 bf16
  {
    const unsigned short* wsrc = W2 + kbase;
#pragma unroll
    for (int j = 0; j < 16; ++j) {
      const int e = (tid + j * 512) * 8;   // 0..65528, covers 64x1024
      const int r = e >> 10, cc = e & 1023;
      const uint4 v = *(const uint4*)(wsrc + (size_t)r * 4096 + cc);
      *(uint4*)&Bs[r * LDB + cc] = v;
    }
  }
  // Order LDS writes for all waves; do NOT drain vmcnt (A ring stays hot).
  __asm__ __volatile__("s_waitcnt lgkmcnt(0)\n\ts_barrier" ::: "memory");

  floatx4 acc0 = {0.f, 0.f, 0.f, 0.f};
  floatx4 acc1 = acc0, acc2 = acc0, acc3 = acc0;

  const unsigned short* bsr = &Bs[frow * LDB + fk];

#define CORE(SL, C)                                                          \
    shortx8 af;                                                              \
    af[0] = (short)f2bf_rne(al##SL.x); af[1] = (short)f2bf_rne(al##SL.y);    \
    af[2] = (short)f2bf_rne(al##SL.z); af[3] = (short)f2bf_rne(al##SL.w);    \
    af[4] = (short)f2bf_rne(ah##SL.x); af[5] = (short)f2bf_rne(ah##SL.y);    \
    af[6] = (short)f2bf_rne(ah##SL.z); af[7] = (short)f2bf_rne(ah##SL.w);    \
    {                                                                        \
      shortx8 bf0 = *(const shortx8*)(bsr + 0 * 16 * LDB + (C) * 32);        \
      shortx8 bf1 = *(const shortx8*)(bsr + 1 * 16 * LDB + (C) * 32);        \
      shortx8 bf2 = *(const shortx8*)(bsr + 2 * 16 * LDB + (C) * 32);        \
      shortx8 bf3 = *(const shortx8*)(bsr + 3 * 16 * LDB + (C) * 32);        \
      acc0 = __builtin_amdgcn_mfma_f32_16x16x32_bf16(af, bf0, acc0, 0, 0, 0);\
      acc1 = __builtin_amdgcn_mfma_f32_16x16x32_bf16(af, bf1, acc1, 0, 0, 0);\
      acc2 = __builtin_amdgcn_mfma_f32_16x16x32_bf16(af, bf2, acc2, 0, 0, 0);\
      acc3 = __builtin_amdgcn_mfma_f32_16x16x32_bf16(af, bf3, acc3, 0, 0, 0);\
    }

#define STEPP(SL, C)                                                         \
  do {                                                                       \
    CORE(SL, C)                                                              \
    al##SL = *(const float4*)(aptr + ((C) + 4) * 32);                        \
    ah##SL = *(const float4*)(aptr + ((C) + 4) * 32 + 4);                    \
  } while (0)

#define STEPN(SL, C) do { CORE(SL, C) } while (0)

  for (int c = 0; c < 28; c += 4) {     // last iter (c=24) prefetches 28..31
    STEPP(0, c);
    STEPP(1, c + 1);
    STEPP(2, c + 2);
    STEPP(3, c + 3);
  }
  STEPN(0, 28);
  STEPN(1, 29);
  STEPN(2, 30);
  STEPN(3, 31);
#undef STEPP
#undef STEPN
#undef CORE

  // store partials: part[kb][m0 + (lane>>4)*4 + r][nt*16 + (lane&15)]
  float* pp = part + (((size_t)kb * 8192 + m0) << 6);
  const int prow = (lane >> 4) * 4;
  const int pcol = lane & 15;
#define ST(NT, ACC)                                                          \
  _Pragma("unroll")                                                          \
  for (int r = 0; r < 4; ++r)                                                \
    pp[(prow + r) * 64 + (NT) * 16 + pcol] = ACC[r];
  ST(0, acc0) ST(1, acc1) ST(2, acc2) ST(3, acc3)
#undef ST
}

// Reduce 4 K-partials + bias + leaky -> out. 131072 threads x float4.
__global__ __launch_bounds__(256) void reduce_kernel(
    const float* __restrict__ part, const float* __restrict__ bias,
    float* __restrict__ out) {
  const int o = (blockIdx.x * 256 + threadIdx.x) * 4;   // 0..524284
  const float4 s0 = *(const float4*)(part + o);
  const float4 s1 = *(const float4*)(part + 524288 + o);
  const float4 s2 = *(const float4*)(part + 1048576 + o);
  const float4 s3 = *(const float4*)(part + 1572864 + o);
  const float4 bv = *(const float4*)(bias + (o & 63));
  float4 r;
  r.x = s0.x + s1.x + s2.x + s3.x + bv.x;
  r.y = s0.y + s1.y + s2.y + s3.y + bv.y;
  r.z = s0.z + s1.z + s2.z + s3.z + bv.z;
  r.w = s0.w + s1.w + s2.w + s3.w + bv.w;
  r.x = (r.x >= 0.f) ? r.x : 1.0e-3f * r.x;
  r.y = (r.y >= 0.f) ? r.y : 1.0e-3f * r.y;
  r.z = (r.z >= 0.f) ? r.z : 1.0e-3f * r.z;
  r.w = (r.w >= 0.f) ? r.w : 1.0e-3f * r.w;
  *(float4*)(out + o) = r;
}

extern "C" void kernel_launch(void* const* d_in, const int* in_sizes, int n_in,
                              void* d_out, int out_size, void* d_ws, size_t ws_size,
                              hipStream_t stream) {
  const float* x      = (const float*)d_in[0];  // [8192,1,64,8,8]
  const float* conv_w = (const float*)d_in[1];  // [64,84,8,8]
  const float* conv_b = (const float*)d_in[2];  // [64]
  float* out = (float*)d_out;                   // [8192,64]

  unsigned short* W2 = (unsigned short*)d_ws;            // 512 KB
  float* part = (float*)((char*)d_ws + (1 << 20));       // 4*8192*64 fp32 = 8 MB

  build_w2_fused<<<dim3(64, 4), 256, 0, stream>>>(conv_w, W2);
  gemm_kernel<<<dim3(64, 4), 512, 0, stream>>>(x, W2, part);
  reduce_kernel<<<512, 256, 0, stream>>>(part, conv_b, out);
}

// Round 6
// 201.535 us; speedup vs baseline: 1.0603x; 1.0603x over previous
//
#include <hip/hip_runtime.h>

typedef __attribute__((ext_vector_type(4))) float floatx4;
typedef __attribute__((ext_vector_type(8))) short shortx8;

// db4 analysis filters, TRUE-convolution orientation:
// y[m] = sum_i F[i] * xp[2m + 7 - i]  (xp reflect-padded, pl = 6 at every level)
__device__ __constant__ float DLO[8] = {
    -0.010597401784997278f, 0.032883011666982945f,
     0.030841381835986965f, -0.18703481171888114f,
    -0.02798376941698385f,  0.6308807679295904f,
     0.7148465705525415f,   0.23037781330885523f};
__device__ __constant__ float DHI[8] = {
    -0.23037781330885523f,  0.7148465705525415f,
    -0.6308807679295904f,  -0.02798376941698385f,
     0.18703481171888114f,  0.030841381835986965f,
     0.032883011666982945f, -0.010597401784997278f};

__device__ __forceinline__ unsigned short f2bf_rne(float f) {
  unsigned u = __builtin_bit_cast(unsigned, f);
  unsigned r = (u + 0x7FFFu + ((u >> 16) & 1u)) >> 16;
  return (unsigned short)r;
}

// One analysis filter-bank level. pl (left reflect pad) == 6 for n in {64,35,21}.
template <int N, int OUT>
__device__ __forceinline__ void afb(const float* x, float* lo, float* hi) {
#pragma unroll
  for (int m = 0; m < OUT; ++m) {
    float aL = 0.f, aH = 0.f;
#pragma unroll
    for (int i = 0; i < 8; ++i) {
      int s = 2 * m + 1 - i;              // 2m + 7 - i - 6
      s = (s < 0) ? -s : s;               // reflect (no edge repeat)
      s = (s >= N) ? (2 * N - 2 - s) : s;
      float v = x[s];
      aL = fmaf(DLO[i], v, aL);
      aH = fmaf(DHI[i], v, aH);
    }
    lo[m] = aL; hi[m] = aH;
  }
}

// Fused M-build + W2-build (verified rounds 2/3/4).
// grid (64, 4), 256 threads. blockIdx.x = k, blockIdx.y = 16-wide tp slice.
// W2[k][tp*64+hw] = sum_t M[t][tp] * conv_w[k][t][hw], rounded to bf16.
__global__ __launch_bounds__(256) void build_w2_fused(
    const float* __restrict__ cw, unsigned short* __restrict__ W2) {
  __shared__ float Ml[84 * 64];
  __shared__ float Cl[84 * 64];
  const int k = blockIdx.x;
  const int tid = threadIdx.x;

  if (tid < 64) {  // column tid of M = DWT(e_tid)
    const int i = tid;
    float sig[64];
#pragma unroll
    for (int t = 0; t < 64; ++t) sig[t] = (t == i) ? 1.f : 0.f;
    float lo1[35], hi1[35], lo2[21], hi2[21], lo3[14], hi3[14];
    afb<64, 35>(sig, lo1, hi1);
    afb<35, 21>(lo1, lo2, hi2);
    afb<21, 14>(lo2, lo3, hi3);
#pragma unroll
    for (int t = 0; t < 14; ++t) Ml[t * 64 + i] = lo3[t];
#pragma unroll
    for (int t = 0; t < 35; ++t) Ml[(14 + t) * 64 + i] = hi1[t];
#pragma unroll
    for (int t = 0; t < 21; ++t) Ml[(49 + t) * 64 + i] = hi2[t];
#pragma unroll
    for (int t = 0; t < 14; ++t) Ml[(70 + t) * 64 + i] = hi3[t];
  }
  const float* cwk = cw + (size_t)k * (84 * 64);
  for (int idx = tid; idx < 84 * 64; idx += 256) Cl[idx] = cwk[idx];
  __syncthreads();

  const int tp  = blockIdx.y * 16 + (tid >> 4);
  const int hw0 = (tid & 15) * 4;
  float a0 = 0.f, a1 = 0.f, a2 = 0.f, a3 = 0.f;
#pragma unroll 4
  for (int t = 0; t < 84; ++t) {
    const float mv = Ml[t * 64 + tp];
    const float4 cv = *(const float4*)&Cl[t * 64 + hw0];
    a0 = fmaf(mv, cv.x, a0);
    a1 = fmaf(mv, cv.y, a1);
    a2 = fmaf(mv, cv.z, a2);
    a3 = fmaf(mv, cv.w, a3);
  }
  uint2 pk;
  pk.x = (unsigned)f2bf_rne(a0) | ((unsigned)f2bf_rne(a1) << 16);
  pk.y = (unsigned)f2bf_rne(a2) | ((unsigned)f2bf_rne(a3) << 16);
  *(uint2*)(W2 + (size_t)k * 4096 + tp * 64 + hw0) = pk;
}

// Streaming GEMM (round-0 structure, measured best): out[8192][64] =
// leaky(A[8192][4096] * W2[64][4096]^T + b). ONE change vs round 0:
// A global loads are NON-TEMPORAL. The 512 MiB workspace poison leaves
// ~L3-capacity of dirty lines; cached A-reads evicted them and the gemm
// window inherited ~170+ MB of writeback (round-2 gemm row: WRITE_SIZE
// 171 MB for a 2 MB-output kernel). nt A-loads skip cache allocation, so
// the poison stays resident and is overwritten in place by the next fill;
// W2 also stops being thrashed out of L2 by the A stream.
#define BM 32
#define BN 64
#define BK 128
#define LDK 136   // +8 bf16 pad: frag-read row stride 272B -> 2-way bank alias (free)
#define NITER 32  // 4096 / BK

__global__ __launch_bounds__(512) void gemm_kernel(
    const float* __restrict__ A, const unsigned short* __restrict__ W2,
    const float* __restrict__ bias, float* __restrict__ out) {
  __shared__ alignas(16) short As[2][BM * LDK];
  __shared__ alignas(16) short Bs[2][BN * LDK];

  const int tid = threadIdx.x;
  const int b0 = blockIdx.x * BM;

  // staging maps
  const int ar = tid >> 4;             // 0..31  (A row in tile)
  const int ac = (tid & 15) * 8;       // 0..120 (A col in chunk, 8 floats)
  const int bn = tid >> 3;             // 0..63  (W2 row)
  const int bc = (tid & 7) * 16;       // 0..112 (16 bf16)

  const float* aptr = A + (size_t)(b0 + ar) * 4096 + ac;
  const unsigned short* bptr = W2 + (size_t)bn * 4096 + bc;

  // mfma tile assignment: 8 waves -> 2 mtiles x 4 ntiles of 16x16
  const int lane = tid & 63;
  const int wave = tid >> 6;
  const int mt = wave >> 2;
  const int nt = wave & 3;
  const int frow = lane & 15;
  const int fk = (lane >> 4) * 8;

  floatx4 acc = {0.f, 0.f, 0.f, 0.f};

  // depth-2 register prefetch (chunks 0 and 1); A loads bypass caches (nt)
  floatx4 a0_0 = __builtin_nontemporal_load((const floatx4*)(aptr + 0));
  floatx4 a1_0 = __builtin_nontemporal_load((const floatx4*)(aptr + 4));
  uint4  b0_0 = *(const uint4*)(bptr + 0);
  uint4  b1_0 = *(const uint4*)(bptr + 8);
  floatx4 a0_1 = __builtin_nontemporal_load((const floatx4*)(aptr + BK));
  floatx4 a1_1 = __builtin_nontemporal_load((const floatx4*)(aptr + BK + 4));
  uint4  b0_1 = *(const uint4*)(bptr + BK);
  uint4  b1_1 = *(const uint4*)(bptr + BK + 8);

  // Raw barrier: lgkmcnt(0) orders LDS writes, but vmcnt is NOT drained, so
  // the depth-2 global prefetches stay in flight across the barrier.
#define GSTEP(S, I)                                                          \
  do {                                                                       \
    shortx8 av;                                                              \
    av[0] = (short)f2bf_rne(a0_##S[0]); av[1] = (short)f2bf_rne(a0_##S[1]);  \
    av[2] = (short)f2bf_rne(a0_##S[2]); av[3] = (short)f2bf_rne(a0_##S[3]);  \
    av[4] = (short)f2bf_rne(a1_##S[0]); av[5] = (short)f2bf_rne(a1_##S[1]);  \
    av[6] = (short)f2bf_rne(a1_##S[2]); av[7] = (short)f2bf_rne(a1_##S[3]);  \
    *(shortx8*)&As[S][ar * LDK + ac] = av;                                   \
    *(uint4*)&Bs[S][bn * LDK + bc] = b0_##S;                                 \
    *(uint4*)&Bs[S][bn * LDK + bc + 8] = b1_##S;                             \
    __asm__ __volatile__("s_waitcnt lgkmcnt(0)\n\ts_barrier" ::: "memory");  \
    if ((I) + 2 < NITER) {                                                   \
      const int c2 = ((I) + 2) * BK;                                         \
      a0_##S = __builtin_nontemporal_load((const floatx4*)(aptr + c2));      \
      a1_##S = __builtin_nontemporal_load((const floatx4*)(aptr + c2 + 4));  \
      b0_##S = *(const uint4*)(bptr + c2);                                   \
      b1_##S = *(const uint4*)(bptr + c2 + 8);                               \
    }                                                                        \
    _Pragma("unroll")                                                        \
    for (int kk = 0; kk < 4; ++kk) {                                         \
      shortx8 af = *(const shortx8*)&As[S][(mt * 16 + frow) * LDK + kk * 32 + fk]; \
      shortx8 bf = *(const shortx8*)&Bs[S][(nt * 16 + frow) * LDK + kk * 32 + fk]; \
      acc = __builtin_amdgcn_mfma_f32_16x16x32_bf16(af, bf, acc, 0, 0, 0);   \
    }                                                                        \
  } while (0)

  for (int i = 0; i < NITER; i += 2) {
    GSTEP(0, i);
    GSTEP(1, i + 1);
  }
#undef GSTEP

  // epilogue: D layout col = lane&15 (n), row = (lane>>4)*4 + r (m)
  const int ocol = nt * 16 + (lane & 15);
  const int orow0 = b0 + mt * 16 + (lane >> 4) * 4;
  const float bv = bias[ocol];
#pragma unroll
  for (int r = 0; r < 4; ++r) {
    float v = acc[r] + bv;
    out[(size_t)(orow0 + r) * 64 + ocol] = (v >= 0.f) ? v : 1.0e-3f * v;
  }
}

extern "C" void kernel_launch(void* const* d_in, const int* in_sizes, int n_in,
                              void* d_out, int out_size, void* d_ws, size_t ws_size,
                              hipStream_t stream) {
  const float* x      = (const float*)d_in[0];  // [8192,1,64,8,8]
  const float* conv_w = (const float*)d_in[1];  // [64,84,8,8]
  const float* conv_b = (const float*)d_in[2];  // [64]
  float* out = (float*)d_out;                   // [8192,64]

  unsigned short* W2 = (unsigned short*)d_ws;   // 64*4096 bf16 = 512 KB

  build_w2_fused<<<dim3(64, 4), 256, 0, stream>>>(conv_w, W2);
  gemm_kernel<<<256, 512, 0, stream>>>(x, W2, conv_b, out);
}